// Round 11
// baseline (240.869 us; speedup 1.0000x reference)
//
#include <hip/hip_runtime.h>
#include <hip/hip_bf16.h>

#define T_WIN 336
#define T_OUT 48
#define T_S   168
#define BM    128
#define CH    782

typedef __attribute__((ext_vector_type(8))) short short8;
typedef __attribute__((ext_vector_type(4))) float f32x4;

__device__ __forceinline__ short f2bf(float f) {
    union { float f; unsigned u; } v; v.f = f;
    unsigned r = v.u + 0x7FFFu + ((v.u >> 16) & 1u);
    return (short)(r >> 16);
}

template <int CTRL, int RMASK>
__device__ __forceinline__ float dppf(float v) {
    union { float f; int i; } in, out;
    in.f = v;
    out.i = __builtin_amdgcn_update_dpp(0, in.i, CTRL, RMASK, 0xf, true);
    return out.f;
}

// write-through relaxed agent store (prep outputs only; off critical path)
__device__ __forceinline__ void st_wt(float* p, float v) {
    __hip_atomic_store(p, v, __ATOMIC_RELAXED, __HIP_MEMORY_SCOPE_AGENT);
}
__device__ __forceinline__ void st_wt_u(unsigned* p, unsigned v) {
    __hip_atomic_store(p, v, __ATOMIC_RELAXED, __HIP_MEMORY_SCOPE_AGENT);
}

// CU identity: HW_ID bits [15:8] + XCC_ID. Wrong decode is SAFE (no park).
__device__ __forceinline__ int my_cu_id() {
    unsigned hwid = __builtin_amdgcn_s_getreg((15 << 11) | (0 << 6) | 4);   // HW_REG_HW_ID, 16b
    unsigned xcc  = __builtin_amdgcn_s_getreg((3 << 11) | (0 << 6) | 20);   // HW_REG_XCC_ID, 4b
    return (int)(((hwid >> 8) & 0xFFu) | (xcc << 8)) + 1;                   // +1: 0 = "unset"
}

__global__ void init_flags(int* flags) {
    if (threadIdx.x < 4) flags[threadIdx.x * 32] = 0;
}

// ===================== fused persistent kernel =====================
// Round-20: deep scan prefetch. r10's CU-park gained ~10us (163->150) but the
// scan still runs ~1.6x stretched under load, invariant to store mechanism
// (r2==r5) — the remaining suspect is x-load latency: depth-2 prefetch covers
// ~1.2us, but with 63 worker blocks hammering the scan XCD's L2, load latency
// inflates to multi-us -> ~0.4us stall/group x 148. Changes vs r10 (one
// mechanism): (1) depth-8 xq register pipeline (~4.9us issue distance,
// vmcnt-cap effective ~3us); (2) publish every 16 groups (9 release drains
// instead of 19 — each release's wave-wide vmcnt(0) drains the deep queue at
// congested latency). All else byte-identical to r10 (park kept).
__global__ __launch_bounds__(256, 2) void fused_kernel(
    const float* __restrict__ x, const float* __restrict__ lvl_coef,
    const float* __restrict__ seas_coef, const float* __restrict__ seas_params,
    const float* __restrict__ W1, const float* __restrict__ W2,
    const float* __restrict__ b1, const float* __restrict__ b2,
    short* __restrict__ W1F, short* __restrict__ W2F,
    float* __restrict__ w_all, float* __restrict__ levels,
    float* __restrict__ cs, float* __restrict__ outp,
    float* __restrict__ lab, float* __restrict__ lpart,
    int* flags, int T, int N, int NB)
{
    __shared__ float Lsf[512];
    __shared__ __align__(16) short Lbf0[512];
    __shared__ __align__(16) short Lbf1[512];
    __shared__ float llv[BM];
    __shared__ __align__(16) short hs[BM * 72];       // 18432 B (loss1 aliases this)
    __shared__ __align__(16) short B1s[11 * 4 * 512]; // 45056 B
    __shared__ __align__(16) short B2s[6 * 512];      // 6144 B
    __shared__ int sh_tk;

    int blk = blockIdx.x;
    int tid = threadIdx.x;
    int* progress  = flags;       // groups published; 1000 = all done
    int* prep_done = flags + 32;  // +128B: prep blocks finished (target 302)
    int* ticket    = flags + 64;  // +256B: dynamic tile dispenser
    int* scan_cu   = flags + 96;  // +384B: scan block's CU identity (+1)

    if (blk == 0) {
        // ---- serial ES scan (one wave, DPP affine scan, sync-free) ----
        if (tid >= 64) return;
        __builtin_amdgcn_s_setprio(3);
        int lane = tid;
        if (lane == 0)
            __hip_atomic_store(scan_cu, my_cu_id(), __ATOMIC_RELAXED, __HIP_MEMORY_SCOPE_AGENT);
        float a = 1.f / (1.f + __expf(-lvl_coef[0]));
        float g = 1.f / (1.f + __expf(-seas_coef[0]));
        float q = 1.f - a, gq = 1.f - g;

        for (int t = lane; t < T_S + 1; t += 64) w_all[t] = __expf(seas_params[t % T_S]);
        float lvl = x[0] / __expf(seas_params[0]);
        if (lane == 0) levels[0] = lvl;

        float wcur[3];
        #pragma unroll
        for (int i = 0; i < 3; ++i)
            wcur[i] = __expf(seas_params[(1 + 3 * lane + i) % T_S]);

        float f1 = q * q * q;
        float f2 = f1 * f1, f4 = f2 * f2, f8 = f4 * f4;
        float lnq = __logf(q);
        float P15 = __expf(3.f * (float)((lane & 15) + 1) * lnq);
        float P31 = __expf(3.f * (float)((lane & 31) + 1) * lnq);
        float pw3l = __expf(3.f * (float)lane * lnq);

        int j0 = 3 * lane;

        auto do_chunk = [&](float xv0, float xv1, float xv2, float* lev) {
            float rr[3];
            rr[0] = a * xv0 * __builtin_amdgcn_rcpf(wcur[0]);
            rr[1] = a * xv1 * __builtin_amdgcn_rcpf(wcur[1]);
            rr[2] = a * xv2 * __builtin_amdgcn_rcpf(wcur[2]);
            float S = fmaf(q, fmaf(q, rr[0], rr[1]), rr[2]);
            S = fmaf(f1, dppf<0x111, 0xf>(S), S);   // row_shr:1
            S = fmaf(f2, dppf<0x112, 0xf>(S), S);   // row_shr:2
            S = fmaf(f4, dppf<0x114, 0xf>(S), S);   // row_shr:4
            S = fmaf(f8, dppf<0x118, 0xf>(S), S);   // row_shr:8
            S = fmaf(P15, dppf<0x142, 0xa>(S), S);  // row_bcast:15 -> rows 1,3
            S = fmaf(P31, dppf<0x143, 0xc>(S), S);  // row_bcast:31 -> rows 2,3
            float E = dppf<0x138, 0xf>(S);          // wave_shr:1 (exclusive)
            float lv = fmaf(pw3l, lvl, E);
            #pragma unroll
            for (int i = 0; i < 3; ++i) { lv = fmaf(q, lv, rr[i]); lev[i] = lv; }
            { union { float f; int i; } uu; uu.i = __builtin_amdgcn_readlane(__builtin_bit_cast(int, lev[2]), 55); lvl = uu.f; }
            wcur[0] = fmaf(gq, wcur[0], g * xv0 * __builtin_amdgcn_rcpf(lev[0]));
            wcur[1] = fmaf(gq, wcur[1], g * xv1 * __builtin_amdgcn_rcpf(lev[1]));
            wcur[2] = fmaf(gq, wcur[2], g * xv2 * __builtin_amdgcn_rcpf(lev[2]));
        };

        // depth-8 group prefetch pipeline (round-20)
        float xq[8][4][3];
        #pragma unroll
        for (int d = 0; d < 8; ++d)
            #pragma unroll
            for (int u = 0; u < 4; ++u)
                #pragma unroll
                for (int i = 0; i < 3; ++i)
                    xq[d][u][i] = x[1 + T_S * (4 * d + u) + j0 + i];

        const float* px = x + 1 + 32 * T_S + j0;   // group 8 base
        float* pl = levels + 1 + j0;
        float* pw = w_all + 1 + T_S + j0;

        for (int grp = 0; grp < 148; ++grp) {
            // publish: RELEASE agent store (vmcnt drain + wbl2 + store),
            // every 16 groups -> 9 drains total.
            if (grp && (grp & 15) == 0 && lane == 0)
                __hip_atomic_store(progress, grp, __ATOMIC_RELEASE, __HIP_MEMORY_SCOPE_AGENT);

            float xnew[4][3];
            if (grp < 140) {
                #pragma unroll
                for (int u = 0; u < 4; ++u)
                    #pragma unroll
                    for (int i = 0; i < 3; ++i)
                        xnew[u][i] = px[u * T_S + i];
            } else {
                #pragma unroll
                for (int u = 0; u < 4; ++u)
                    #pragma unroll
                    for (int i = 0; i < 3; ++i) {
                        int t = 1 + T_S * (4 * (grp + 8) + u) + j0 + i;
                        xnew[u][i] = x[min(t, T - 1)];
                    }
            }
            px += 4 * T_S;

            #pragma unroll
            for (int u = 0; u < 4; ++u) {
                float lev[3];
                do_chunk(xq[0][u][0], xq[0][u][1], xq[0][u][2], lev);
                #pragma unroll
                for (int i = 0; i < 3; ++i) {
                    pl[u * T_S + i] = lev[i];
                    pw[u * T_S + i] = wcur[i];
                }
            }
            pl += 4 * T_S; pw += 4 * T_S;

            #pragma unroll
            for (int d = 0; d < 7; ++d)
                #pragma unroll
                for (int u = 0; u < 4; ++u)
                    #pragma unroll
                    for (int i = 0; i < 3; ++i)
                        xq[d][u][i] = xq[d + 1][u][i];
            #pragma unroll
            for (int u = 0; u < 4; ++u)
                #pragma unroll
                for (int i = 0; i < 3; ++i)
                    xq[7][u][i] = xnew[u][i];
        }

        // tail: chunks 592..595 (xq[0] holds group 148), guarded stores
        #pragma unroll
        for (int u = 0; u < 4; ++u) {
            int c = 592 + u;
            if (c * T_S >= T - 1) break;
            int len = (T - 1) - T_S * c; if (len > T_S) len = T_S;
            float lev[3];
            do_chunk(xq[0][u][0], xq[0][u][1], xq[0][u][2], lev);
            #pragma unroll
            for (int i = 0; i < 3; ++i) {
                if (j0 + i < len) {
                    pl[u * T_S + i] = lev[i];
                    pw[u * T_S + i] = wcur[i];
                }
            }
        }
        if (lane == 0)
            __hip_atomic_store(progress, 1000, __ATOMIC_RELEASE, __HIP_MEMORY_SCOPE_AGENT);
        return;
    }

    if (blk <= 302) {
        if (blk >= 301) {              // ---- cs: colsum of W1 ----
            int k = (blk - 301) * 256 + tid;
            if (k < T_WIN) {
                float s = 0.f;
                for (int j = 0; j < T_WIN; ++j) s += W1[j * T_WIN + k];
                st_wt(&cs[k], s);
            }
        } else if (blk >= 265) {       // ---- W2F ----
            int d = (blk - 265) * 256 + tid;
            int j2 = d & 3, lane = (d >> 2) & 63, f = d >> 8;
            int ct2 = f % 3, rest = f / 3;
            int kt2 = rest & 1, c = rest >> 1;
            int k = c * 64 + kt2 * 32 + (lane >> 4) * 8 + 2 * j2;
            int o = ct2 * 16 + (lane & 15);
            unsigned short lo = 0, hi = 0;
            if (k     < T_WIN) lo = (unsigned short)f2bf(W2[k * T_OUT + o]);
            if (k + 1 < T_WIN) hi = (unsigned short)f2bf(W2[(k + 1) * T_OUT + o]);
            st_wt_u(&((unsigned*)W2F)[d], ((unsigned)hi << 16) | (unsigned)lo);
        } else {                       // ---- W1F ----
            int d = (blk - 1) * 256 + tid;
            int j2 = d & 3, lane = (d >> 2) & 63, f = d >> 8;
            int ct = f & 3, rest = f >> 2;
            int kt = rest % 11, c = rest / 11;
            int k = kt * 32 + (lane >> 4) * 8 + 2 * j2;
            int col = c * 64 + ct * 16 + (lane & 15);
            unsigned short lo = 0, hi = 0;
            if (col < T_WIN) {
                if (k     < T_WIN) lo = (unsigned short)f2bf(W1[k * T_WIN + col]);
                if (k + 1 < T_WIN) hi = (unsigned short)f2bf(W1[(k + 1) * T_WIN + col]);
            }
            st_wt_u(&((unsigned*)W1F)[d], ((unsigned)hi << 16) | (unsigned)lo);
        }
        __syncthreads();   // per-wave vmcnt drained before s_barrier
        if (tid == 0)
            __hip_atomic_fetch_add(prep_done, 1, __ATOMIC_RELAXED, __HIP_MEMORY_SCOPE_AGENT);
        // fall through to worker loop
    }

    // ================= worker loop (blocks 1..511) =================
    if (tid < 64) {
        while (__hip_atomic_load(prep_done, __ATOMIC_RELAXED, __HIP_MEMORY_SCOPE_AGENT) < 302)
            __builtin_amdgcn_s_sleep(16);
    }
    __syncthreads();   // W1F/W2F/cs at MALL; never stale-cached here

    int lane = tid & 63, wv = tid >> 6;
    int lr = lane & 15, lq = lane >> 4;
    int rw = wv * 32;
    int last_seen = 0;
    int NT = NB + 128;

    // ---- park if this block shares the scan's CU (r10: +10us) ----
    {
        int mine = my_cu_id();
        if (__hip_atomic_load(scan_cu, __ATOMIC_RELAXED, __HIP_MEMORY_SCOPE_AGENT) == mine) {
            while (__hip_atomic_load(progress, __ATOMIC_RELAXED, __HIP_MEMORY_SCOPE_AGENT) < 1000)
                __builtin_amdgcn_s_sleep(64);
            last_seen = 1000;
        }
    }

    for (;;) {
        __syncthreads();   // prior tile's LDS consumers done; sh_tk reusable
        if (tid == 0) sh_tk = atomicAdd(ticket, 1);
        __syncthreads();
        int tk = sh_tk;
        if (tk >= NT) return;

        // ---- ticket -> tile: interleave loss1 tiles 1-in-7 ----
        int sev = tk / 7;
        bool isl = (tk % 7 == 6) && (sev < 128);
        int tile = isl ? (NB + sev) : (tk - min(sev, 128));

        // ---- wait for scan frontier (+128-float pad for line tails) ----
        int need_t = (tile < NB) ? (tile * BM + 512 + 128)
                                 : ((tile - NB) * CH + CH + 2 + 128);
        if (need_t > T) need_t = T;
        int req = (need_t + 670) / 672;
        if (last_seen < req) {
            if (tid < 64) {
                while (__hip_atomic_load(progress, __ATOMIC_RELAXED, __HIP_MEMORY_SCOPE_AGENT) < req)
                    __builtin_amdgcn_s_sleep(32);
            }
            __syncthreads();
            last_seen = req;
        }

        if (tile >= NB) {
            // ---------------- loss1 tile ----------------
            float* ls  = (float*)hs;
            float* red = (float*)(hs + 4096);
            int lb = tile - NB;
            int lo = lb * CH;
            int n = T - lo; if (n > CH + 2) n = CH + 2;
            for (int i = tid; i < n; i += 256) ls[i] = __logf(levels[lo + i]);
            __syncthreads();
            float s = 0.f;
            int dmax = (T - 2) - lo; if (dmax > CH) dmax = CH;
            for (int i = tid; i < dmax; i += 256) {
                float d = ls[i + 2] - 2.f * ls[i + 1] + ls[i];
                s = fmaf(d, d, s);
            }
            red[tid] = s;
            __syncthreads();
            for (int w = 128; w > 0; w >>= 1) {
                if (tid < w) red[tid] += red[tid + w];
                __syncthreads();
            }
            if (tid == 0) lpart[lb] = red[0];
            continue;
        }

        // ---------------- gemm tile ----------------
        int n0 = tile * BM;
        float C = __logf(levels[min(n0 + T_WIN, T - 1)]);

        for (int i = tid; i < 512; i += 256) {
            int t = n0 + i;
            float v = (t < T) ? (__logf(x[t]) - __logf(w_all[t]) - C) : 0.f;
            Lsf[i] = v;
            Lbf0[i] = f2bf(v);
        }
        for (int i = tid; i < BM; i += 256) {
            int t = n0 + i + T_WIN;
            llv[i] = (t < T) ? (__logf(levels[t]) - C) : 0.f;
        }
        __syncthreads();
        for (int i = tid; i < 512; i += 256) Lbf1[i] = (i < 511) ? Lbf0[i + 1] : (short)0;
        __syncthreads();

        for (int u2 = tid; u2 < BM * T_OUT; u2 += 256) {
            int row = u2 / T_OUT, j = u2 - row * T_OUT;
            int nn = n0 + row;
            if (nn < N) lab[(size_t)nn * T_OUT + j] = Lsf[row + T_WIN + j] - llv[row];
        }

        // pack 22 A-fragments (parity arrays: 4B-aligned b32 reads)
        const short* abase = ((lr & 1) ? Lbf1 : Lbf0) + rw + (lr & ~1);
        short8 af[11][2];
        #pragma unroll
        for (int kt = 0; kt < 11; ++kt) {
            #pragma unroll
            for (int mt = 0; mt < 2; ++mt) {
                const int* ip = (const int*)(abase + mt * 16 + kt * 32 + lq * 8);
                union { short8 s; int i[4]; } u;
                u.i[0] = ip[0]; u.i[1] = ip[1]; u.i[2] = ip[2]; u.i[3] = ip[3];
                af[kt][mt] = u.s;
            }
        }

        f32x4 zero4 = {0.f, 0.f, 0.f, 0.f};
        f32x4 acc2[2][3];
        #pragma unroll
        for (int mt = 0; mt < 2; ++mt)
            #pragma unroll
            for (int ct = 0; ct < 3; ++ct) acc2[mt][ct] = zero4;

        #pragma unroll 1
        for (int c = 0; c < 6; ++c) {
            __syncthreads();   // previous chunk's B1s/B2s/hs consumers done

            const char* g1 = (const char*)(W1F + (size_t)c * 11 * 4 * 512);
            for (int seg = wv; seg < 44; seg += 4) {
                __builtin_amdgcn_global_load_lds(
                    (const __attribute__((address_space(1))) unsigned int*)(g1 + seg * 1024 + lane * 16),
                    (__attribute__((address_space(3))) unsigned int*)((char*)B1s + seg * 1024),
                    16, 0, 0);
            }
            const char* g2 = (const char*)(W2F + (size_t)c * 6 * 512);
            for (int seg = wv; seg < 6; seg += 4) {
                __builtin_amdgcn_global_load_lds(
                    (const __attribute__((address_space(1))) unsigned int*)(g2 + seg * 1024 + lane * 16),
                    (__attribute__((address_space(3))) unsigned int*)((char*)B2s + seg * 1024),
                    16, 0, 0);
            }
            float b1v[4], csv[4];
            #pragma unroll
            for (int ct = 0; ct < 4; ++ct) {
                int col = c * 64 + ct * 16 + lr;
                b1v[ct] = (col < T_WIN) ? b1[col] : 0.f;
                csv[ct] = (col < T_WIN) ? cs[col] : 0.f;
            }
            __syncthreads();   // staging visible (vmcnt drained)

            f32x4 acc1[2][4];
            #pragma unroll
            for (int mt = 0; mt < 2; ++mt)
                #pragma unroll
                for (int ct = 0; ct < 4; ++ct) acc1[mt][ct] = zero4;

            #pragma unroll
            for (int kt = 0; kt < 11; ++kt) {
                #pragma unroll
                for (int ct = 0; ct < 4; ++ct) {
                    short8 bf = *(const short8*)&B1s[((kt * 4 + ct) * 64 + lane) * 8];
                    acc1[0][ct] = __builtin_amdgcn_mfma_f32_16x16x32_bf16(af[kt][0], bf, acc1[0][ct], 0, 0, 0);
                    acc1[1][ct] = __builtin_amdgcn_mfma_f32_16x16x32_bf16(af[kt][1], bf, acc1[1][ct], 0, 0, 0);
                }
            }

            // epilogue -> hs (wave-local rows; no extra barrier)
            #pragma unroll
            for (int mt = 0; mt < 2; ++mt)
                #pragma unroll
                for (int ct = 0; ct < 4; ++ct)
                    #pragma unroll
                    for (int r = 0; r < 4; ++r) {
                        int row = rw + mt * 16 + lq * 4 + r;
                        float pre = acc1[mt][ct][r] + b1v[ct] - llv[row] * csv[ct];
                        float e = __expf(2.f * pre);
                        float h = 1.f - 2.f * __builtin_amdgcn_rcpf(e + 1.f);
                        hs[row * 72 + ct * 16 + lr] = f2bf(h);
                    }

            #pragma unroll
            for (int kt2 = 0; kt2 < 2; ++kt2) {
                short8 a2[2];
                #pragma unroll
                for (int mt = 0; mt < 2; ++mt)
                    a2[mt] = *(const short8*)&hs[(rw + mt * 16 + lr) * 72 + kt2 * 32 + lq * 8];
                #pragma unroll
                for (int ct2 = 0; ct2 < 3; ++ct2) {
                    short8 bf2 = *(const short8*)&B2s[((kt2 * 3 + ct2) * 64 + lane) * 8];
                    acc2[0][ct2] = __builtin_amdgcn_mfma_f32_16x16x32_bf16(a2[0], bf2, acc2[0][ct2], 0, 0, 0);
                    acc2[1][ct2] = __builtin_amdgcn_mfma_f32_16x16x32_bf16(a2[1], bf2, acc2[1][ct2], 0, 0, 0);
                }
            }
        }

        float b2v[3];
        #pragma unroll
        for (int ct2 = 0; ct2 < 3; ++ct2) b2v[ct2] = b2[ct2 * 16 + lr];
        #pragma unroll
        for (int mt = 0; mt < 2; ++mt)
            #pragma unroll
            for (int ct2 = 0; ct2 < 3; ++ct2)
                #pragma unroll
                for (int r = 0; r < 4; ++r) {
                    int row = n0 + rw + mt * 16 + lq * 4 + r;
                    if (row < N)
                        outp[(size_t)row * T_OUT + ct2 * 16 + lr] = acc2[mt][ct2][r] + b2v[ct2];
                }
    }
}

__global__ __launch_bounds__(128) void loss2_kernel(
    const float* __restrict__ part, const int* __restrict__ lvp,
    float* __restrict__ out_loss, int T)
{
    __shared__ float red[128];
    red[threadIdx.x] = part[threadIdx.x];
    __syncthreads();
    for (int w = 64; w > 0; w >>= 1) {
        if (threadIdx.x < (unsigned)w) red[threadIdx.x] += red[threadIdx.x + w];
        __syncthreads();
    }
    if (threadIdx.x == 0) out_loss[0] = red[0] * (float)lvp[0] / (float)(T - 2);
}

extern "C" void kernel_launch(void* const* d_in, const int* in_sizes, int n_in,
                              void* d_out, int out_size, void* d_ws, size_t ws_size,
                              hipStream_t stream) {
    const float* x    = (const float*)d_in[0];
    const float* lvlc = (const float*)d_in[1];
    const float* seac = (const float*)d_in[2];
    const float* sp   = (const float*)d_in[3];
    const float* W1   = (const float*)d_in[4];
    const float* b1   = (const float*)d_in[5];
    const float* W2   = (const float*)d_in[6];
    const float* b2   = (const float*)d_in[7];
    const int*   lvp  = (const int*)d_in[10];

    int T = in_sizes[0];
    int N = T - T_WIN - T_OUT + 1;
    int NB = (N + BM - 1) / BM;

    short* W1F    = (short*)d_ws;                  // 264*512 shorts
    short* W2F    = W1F + 264 * 512;               // 36*512 shorts
    float* w_all  = (float*)(W2F + 36 * 512);      // T + 192
    float* levels = w_all + T + 192;               // T
    float* cs     = levels + T;                    // 352
    float* lpart  = cs + 352;                      // 128
    int*   flagsp = (int*)(lpart + 128);           // 4 flags on separate 128B lines

    float* outp  = (float*)d_out;
    float* lab   = outp + (size_t)N * T_OUT;
    float* lossp = lab + (size_t)N * T_OUT;

    init_flags<<<1, 64, 0, stream>>>(flagsp);
    fused_kernel<<<512, 256, 0, stream>>>(x, lvlc, seac, sp, W1, W2, b1, b2,
                                          W1F, W2F, w_all, levels, cs,
                                          outp, lab, lpart, flagsp, T, N, NB);
    loss2_kernel<<<1, 128, 0, stream>>>(lpart, lvp, lossp, T);
}

// Round 13
// 217.370 us; speedup vs baseline: 1.1081x; 1.1081x over previous
//
#include <hip/hip_runtime.h>
#include <hip/hip_bf16.h>

#define T_WIN 336
#define T_OUT 48
#define T_S   168
#define BM    128
#define CH    782

typedef __attribute__((ext_vector_type(8))) short short8;
typedef __attribute__((ext_vector_type(4))) float f32x4;

__device__ __forceinline__ short f2bf(float f) {
    union { float f; unsigned u; } v; v.f = f;
    unsigned r = v.u + 0x7FFFu + ((v.u >> 16) & 1u);
    return (short)(r >> 16);
}

template <int CTRL, int RMASK>
__device__ __forceinline__ float dppf(float v) {
    union { float f; int i; } in, out;
    in.f = v;
    out.i = __builtin_amdgcn_update_dpp(0, in.i, CTRL, RMASK, 0xf, true);
    return out.f;
}

// write-through relaxed agent store (prep outputs only; off critical path)
__device__ __forceinline__ void st_wt(float* p, float v) {
    __hip_atomic_store(p, v, __ATOMIC_RELAXED, __HIP_MEMORY_SCOPE_AGENT);
}
__device__ __forceinline__ void st_wt_u(unsigned* p, unsigned v) {
    __hip_atomic_store(p, v, __ATOMIC_RELAXED, __HIP_MEMORY_SCOPE_AGENT);
}

// CU identity: HW_ID bits [15:8] + XCC_ID. Wrong decode is SAFE (no park).
__device__ __forceinline__ int my_cu_id() {
    unsigned hwid = __builtin_amdgcn_s_getreg((15 << 11) | (0 << 6) | 4);   // HW_REG_HW_ID, 16b
    unsigned xcc  = __builtin_amdgcn_s_getreg((3 << 11) | (0 << 6) | 20);   // HW_REG_XCC_ID, 4b
    return (int)(((hwid >> 8) & 0xFFu) | (xcc << 8)) + 1;                   // +1: 0 = "unset"
}

__global__ void init_flags(int* flags) {
    if (threadIdx.x < 4) flags[threadIdx.x * 32] = 0;
}

// ===================== fused persistent kernel =====================
// Round-21 (2nd submit; round-12 was an infra timeout): depth-4 scan prefetch
// WITHOUT the round-11 mistakes. r11's depth-8 regressed (150->175) because
// (a) xq[8][4][3]=96 floats spilled to scratch (VGPR stayed 104 — impossible
// without spill), (b) 96 outstanding loads exceed the 63-entry vmcnt cap,
// (c) 84 v_movs/group of register shifting. Fix: bufx[4][4][3]=48 VGPR
// (<63 cap, no spill), 37x4 statically-unrolled slot rotation (consume
// bufx[s] -> reissue prefetch g+4 into bufx[s]; all indices compile-time,
// zero shift movs). Publish cadence reverted to every 8 groups (r10).
// CU-park kept. Worker/gemm side byte-identical to r10 (measured best:
// fused ~150, total 221.5).
__global__ __launch_bounds__(256, 2) void fused_kernel(
    const float* __restrict__ x, const float* __restrict__ lvl_coef,
    const float* __restrict__ seas_coef, const float* __restrict__ seas_params,
    const float* __restrict__ W1, const float* __restrict__ W2,
    const float* __restrict__ b1, const float* __restrict__ b2,
    short* __restrict__ W1F, short* __restrict__ W2F,
    float* __restrict__ w_all, float* __restrict__ levels,
    float* __restrict__ cs, float* __restrict__ outp,
    float* __restrict__ lab, float* __restrict__ lpart,
    int* flags, int T, int N, int NB)
{
    __shared__ float Lsf[512];
    __shared__ __align__(16) short Lbf0[512];
    __shared__ __align__(16) short Lbf1[512];
    __shared__ float llv[BM];
    __shared__ __align__(16) short hs[BM * 72];       // 18432 B (loss1 aliases this)
    __shared__ __align__(16) short B1s[11 * 4 * 512]; // 45056 B
    __shared__ __align__(16) short B2s[6 * 512];      // 6144 B
    __shared__ int sh_tk;

    int blk = blockIdx.x;
    int tid = threadIdx.x;
    int* progress  = flags;       // groups published; 1000 = all done
    int* prep_done = flags + 32;  // +128B: prep blocks finished (target 302)
    int* ticket    = flags + 64;  // +256B: dynamic tile dispenser
    int* scan_cu   = flags + 96;  // +384B: scan block's CU identity (+1)

    if (blk == 0) {
        // ---- serial ES scan (one wave, DPP affine scan, sync-free) ----
        if (tid >= 64) return;
        __builtin_amdgcn_s_setprio(3);
        int lane = tid;
        if (lane == 0)
            __hip_atomic_store(scan_cu, my_cu_id(), __ATOMIC_RELAXED, __HIP_MEMORY_SCOPE_AGENT);
        float a = 1.f / (1.f + __expf(-lvl_coef[0]));
        float g = 1.f / (1.f + __expf(-seas_coef[0]));
        float q = 1.f - a, gq = 1.f - g;

        for (int t = lane; t < T_S + 1; t += 64) w_all[t] = __expf(seas_params[t % T_S]);
        float lvl = x[0] / __expf(seas_params[0]);
        if (lane == 0) levels[0] = lvl;

        float wcur[3];
        #pragma unroll
        for (int i = 0; i < 3; ++i)
            wcur[i] = __expf(seas_params[(1 + 3 * lane + i) % T_S]);

        float f1 = q * q * q;
        float f2 = f1 * f1, f4 = f2 * f2, f8 = f4 * f4;
        float lnq = __logf(q);
        float P15 = __expf(3.f * (float)((lane & 15) + 1) * lnq);
        float P31 = __expf(3.f * (float)((lane & 31) + 1) * lnq);
        float pw3l = __expf(3.f * (float)lane * lnq);

        int j0 = 3 * lane;

        auto do_chunk = [&](float xv0, float xv1, float xv2, float* lev) {
            float rr[3];
            rr[0] = a * xv0 * __builtin_amdgcn_rcpf(wcur[0]);
            rr[1] = a * xv1 * __builtin_amdgcn_rcpf(wcur[1]);
            rr[2] = a * xv2 * __builtin_amdgcn_rcpf(wcur[2]);
            float S = fmaf(q, fmaf(q, rr[0], rr[1]), rr[2]);
            S = fmaf(f1, dppf<0x111, 0xf>(S), S);   // row_shr:1
            S = fmaf(f2, dppf<0x112, 0xf>(S), S);   // row_shr:2
            S = fmaf(f4, dppf<0x114, 0xf>(S), S);   // row_shr:4
            S = fmaf(f8, dppf<0x118, 0xf>(S), S);   // row_shr:8
            S = fmaf(P15, dppf<0x142, 0xa>(S), S);  // row_bcast:15 -> rows 1,3
            S = fmaf(P31, dppf<0x143, 0xc>(S), S);  // row_bcast:31 -> rows 2,3
            float E = dppf<0x138, 0xf>(S);          // wave_shr:1 (exclusive)
            float lv = fmaf(pw3l, lvl, E);
            #pragma unroll
            for (int i = 0; i < 3; ++i) { lv = fmaf(q, lv, rr[i]); lev[i] = lv; }
            { union { float f; int i; } uu; uu.i = __builtin_amdgcn_readlane(__builtin_bit_cast(int, lev[2]), 55); lvl = uu.f; }
            wcur[0] = fmaf(gq, wcur[0], g * xv0 * __builtin_amdgcn_rcpf(lev[0]));
            wcur[1] = fmaf(gq, wcur[1], g * xv1 * __builtin_amdgcn_rcpf(lev[1]));
            wcur[2] = fmaf(gq, wcur[2], g * xv2 * __builtin_amdgcn_rcpf(lev[2]));
        };

        // depth-4 static-slot prefetch pipeline (48 VGPR, <63 vmcnt cap, no shifts)
        float bufx[4][4][3];
        #pragma unroll
        for (int d = 0; d < 4; ++d)
            #pragma unroll
            for (int u = 0; u < 4; ++u)
                #pragma unroll
                for (int i = 0; i < 3; ++i)
                    bufx[d][u][i] = x[1 + T_S * (4 * d + u) + j0 + i];

        float* pl = levels + 1 + j0;
        float* pw = w_all + 1 + T_S + j0;

        for (int m = 0; m < 37; ++m) {
            #pragma unroll
            for (int s = 0; s < 4; ++s) {
                int grp = 4 * m + s;
                // publish every 8 groups (19 release drains total, as r10)
                if (grp && (grp & 7) == 0 && lane == 0)
                    __hip_atomic_store(progress, grp, __ATOMIC_RELEASE, __HIP_MEMORY_SCOPE_AGENT);

                // consume slot s into locals
                float xl[4][3];
                #pragma unroll
                for (int u = 0; u < 4; ++u)
                    #pragma unroll
                    for (int i = 0; i < 3; ++i)
                        xl[u][i] = bufx[s][u][i];

                // reissue prefetch for group grp+4 into slot s (static index)
                int gp = grp + 4;
                if (gp < 148) {          // chunks <= 591: raw loads safe
                    const float* pxg = x + 1 + (size_t)(4 * gp) * T_S + j0;
                    #pragma unroll
                    for (int u = 0; u < 4; ++u)
                        #pragma unroll
                        for (int i = 0; i < 3; ++i)
                            bufx[s][u][i] = pxg[u * T_S + i];
                } else {                 // group 148 (tail data) / 149+ (unused)
                    #pragma unroll
                    for (int u = 0; u < 4; ++u)
                        #pragma unroll
                        for (int i = 0; i < 3; ++i) {
                            int t = 1 + T_S * (4 * gp + u) + j0 + i;
                            bufx[s][u][i] = x[min(t, T - 1)];
                        }
                }

                // serial chunk math + stores
                #pragma unroll
                for (int u = 0; u < 4; ++u) {
                    float lev[3];
                    do_chunk(xl[u][0], xl[u][1], xl[u][2], lev);
                    #pragma unroll
                    for (int i = 0; i < 3; ++i) {
                        pl[u * T_S + i] = lev[i];
                        pw[u * T_S + i] = wcur[i];
                    }
                }
                pl += 4 * T_S; pw += 4 * T_S;
            }
        }

        // tail: chunks 592..595 (bufx[0] holds group 148), guarded stores
        #pragma unroll
        for (int u = 0; u < 4; ++u) {
            int c = 592 + u;
            if (c * T_S >= T - 1) break;
            int len = (T - 1) - T_S * c; if (len > T_S) len = T_S;
            float lev[3];
            do_chunk(bufx[0][u][0], bufx[0][u][1], bufx[0][u][2], lev);
            #pragma unroll
            for (int i = 0; i < 3; ++i) {
                if (j0 + i < len) {
                    pl[u * T_S + i] = lev[i];
                    pw[u * T_S + i] = wcur[i];
                }
            }
        }
        if (lane == 0)
            __hip_atomic_store(progress, 1000, __ATOMIC_RELEASE, __HIP_MEMORY_SCOPE_AGENT);
        return;
    }

    if (blk <= 302) {
        if (blk >= 301) {              // ---- cs: colsum of W1 ----
            int k = (blk - 301) * 256 + tid;
            if (k < T_WIN) {
                float s = 0.f;
                for (int j = 0; j < T_WIN; ++j) s += W1[j * T_WIN + k];
                st_wt(&cs[k], s);
            }
        } else if (blk >= 265) {       // ---- W2F ----
            int d = (blk - 265) * 256 + tid;
            int j2 = d & 3, lane = (d >> 2) & 63, f = d >> 8;
            int ct2 = f % 3, rest = f / 3;
            int kt2 = rest & 1, c = rest >> 1;
            int k = c * 64 + kt2 * 32 + (lane >> 4) * 8 + 2 * j2;
            int o = ct2 * 16 + (lane & 15);
            unsigned short lo = 0, hi = 0;
            if (k     < T_WIN) lo = (unsigned short)f2bf(W2[k * T_OUT + o]);
            if (k + 1 < T_WIN) hi = (unsigned short)f2bf(W2[(k + 1) * T_OUT + o]);
            st_wt_u(&((unsigned*)W2F)[d], ((unsigned)hi << 16) | (unsigned)lo);
        } else {                       // ---- W1F ----
            int d = (blk - 1) * 256 + tid;
            int j2 = d & 3, lane = (d >> 2) & 63, f = d >> 8;
            int ct = f & 3, rest = f >> 2;
            int kt = rest % 11, c = rest / 11;
            int k = kt * 32 + (lane >> 4) * 8 + 2 * j2;
            int col = c * 64 + ct * 16 + (lane & 15);
            unsigned short lo = 0, hi = 0;
            if (col < T_WIN) {
                if (k     < T_WIN) lo = (unsigned short)f2bf(W1[k * T_WIN + col]);
                if (k + 1 < T_WIN) hi = (unsigned short)f2bf(W1[(k + 1) * T_WIN + col]);
            }
            st_wt_u(&((unsigned*)W1F)[d], ((unsigned)hi << 16) | (unsigned)lo);
        }
        __syncthreads();   // per-wave vmcnt drained before s_barrier
        if (tid == 0)
            __hip_atomic_fetch_add(prep_done, 1, __ATOMIC_RELAXED, __HIP_MEMORY_SCOPE_AGENT);
        // fall through to worker loop
    }

    // ================= worker loop (blocks 1..511) =================
    if (tid < 64) {
        while (__hip_atomic_load(prep_done, __ATOMIC_RELAXED, __HIP_MEMORY_SCOPE_AGENT) < 302)
            __builtin_amdgcn_s_sleep(16);
    }
    __syncthreads();   // W1F/W2F/cs at MALL; never stale-cached here

    int lane = tid & 63, wv = tid >> 6;
    int lr = lane & 15, lq = lane >> 4;
    int rw = wv * 32;
    int last_seen = 0;
    int NT = NB + 128;

    // ---- park if this block shares the scan's CU (r10: +10us) ----
    {
        int mine = my_cu_id();
        if (__hip_atomic_load(scan_cu, __ATOMIC_RELAXED, __HIP_MEMORY_SCOPE_AGENT) == mine) {
            while (__hip_atomic_load(progress, __ATOMIC_RELAXED, __HIP_MEMORY_SCOPE_AGENT) < 1000)
                __builtin_amdgcn_s_sleep(64);
            last_seen = 1000;
        }
    }

    for (;;) {
        __syncthreads();   // prior tile's LDS consumers done; sh_tk reusable
        if (tid == 0) sh_tk = atomicAdd(ticket, 1);
        __syncthreads();
        int tk = sh_tk;
        if (tk >= NT) return;

        // ---- ticket -> tile: interleave loss1 tiles 1-in-7 ----
        int sev = tk / 7;
        bool isl = (tk % 7 == 6) && (sev < 128);
        int tile = isl ? (NB + sev) : (tk - min(sev, 128));

        // ---- wait for scan frontier (+128-float pad for line tails) ----
        int need_t = (tile < NB) ? (tile * BM + 512 + 128)
                                 : ((tile - NB) * CH + CH + 2 + 128);
        if (need_t > T) need_t = T;
        int req = (need_t + 670) / 672;
        if (last_seen < req) {
            if (tid < 64) {
                while (__hip_atomic_load(progress, __ATOMIC_RELAXED, __HIP_MEMORY_SCOPE_AGENT) < req)
                    __builtin_amdgcn_s_sleep(32);
            }
            __syncthreads();
            last_seen = req;
        }

        if (tile >= NB) {
            // ---------------- loss1 tile ----------------
            float* ls  = (float*)hs;
            float* red = (float*)(hs + 4096);
            int lb = tile - NB;
            int lo = lb * CH;
            int n = T - lo; if (n > CH + 2) n = CH + 2;
            for (int i = tid; i < n; i += 256) ls[i] = __logf(levels[lo + i]);
            __syncthreads();
            float s = 0.f;
            int dmax = (T - 2) - lo; if (dmax > CH) dmax = CH;
            for (int i = tid; i < dmax; i += 256) {
                float d = ls[i + 2] - 2.f * ls[i + 1] + ls[i];
                s = fmaf(d, d, s);
            }
            red[tid] = s;
            __syncthreads();
            for (int w = 128; w > 0; w >>= 1) {
                if (tid < w) red[tid] += red[tid + w];
                __syncthreads();
            }
            if (tid == 0) lpart[lb] = red[0];
            continue;
        }

        // ---------------- gemm tile ----------------
        int n0 = tile * BM;
        float C = __logf(levels[min(n0 + T_WIN, T - 1)]);

        for (int i = tid; i < 512; i += 256) {
            int t = n0 + i;
            float v = (t < T) ? (__logf(x[t]) - __logf(w_all[t]) - C) : 0.f;
            Lsf[i] = v;
            Lbf0[i] = f2bf(v);
        }
        for (int i = tid; i < BM; i += 256) {
            int t = n0 + i + T_WIN;
            llv[i] = (t < T) ? (__logf(levels[t]) - C) : 0.f;
        }
        __syncthreads();
        for (int i = tid; i < 512; i += 256) Lbf1[i] = (i < 511) ? Lbf0[i + 1] : (short)0;
        __syncthreads();

        for (int u2 = tid; u2 < BM * T_OUT; u2 += 256) {
            int row = u2 / T_OUT, j = u2 - row * T_OUT;
            int nn = n0 + row;
            if (nn < N) lab[(size_t)nn * T_OUT + j] = Lsf[row + T_WIN + j] - llv[row];
        }

        // pack 22 A-fragments (parity arrays: 4B-aligned b32 reads)
        const short* abase = ((lr & 1) ? Lbf1 : Lbf0) + rw + (lr & ~1);
        short8 af[11][2];
        #pragma unroll
        for (int kt = 0; kt < 11; ++kt) {
            #pragma unroll
            for (int mt = 0; mt < 2; ++mt) {
                const int* ip = (const int*)(abase + mt * 16 + kt * 32 + lq * 8);
                union { short8 s; int i[4]; } u;
                u.i[0] = ip[0]; u.i[1] = ip[1]; u.i[2] = ip[2]; u.i[3] = ip[3];
                af[kt][mt] = u.s;
            }
        }

        f32x4 zero4 = {0.f, 0.f, 0.f, 0.f};
        f32x4 acc2[2][3];
        #pragma unroll
        for (int mt = 0; mt < 2; ++mt)
            #pragma unroll
            for (int ct = 0; ct < 3; ++ct) acc2[mt][ct] = zero4;

        #pragma unroll 1
        for (int c = 0; c < 6; ++c) {
            __syncthreads();   // previous chunk's B1s/B2s/hs consumers done

            const char* g1 = (const char*)(W1F + (size_t)c * 11 * 4 * 512);
            for (int seg = wv; seg < 44; seg += 4) {
                __builtin_amdgcn_global_load_lds(
                    (const __attribute__((address_space(1))) unsigned int*)(g1 + seg * 1024 + lane * 16),
                    (__attribute__((address_space(3))) unsigned int*)((char*)B1s + seg * 1024),
                    16, 0, 0);
            }
            const char* g2 = (const char*)(W2F + (size_t)c * 6 * 512);
            for (int seg = wv; seg < 6; seg += 4) {
                __builtin_amdgcn_global_load_lds(
                    (const __attribute__((address_space(1))) unsigned int*)(g2 + seg * 1024 + lane * 16),
                    (__attribute__((address_space(3))) unsigned int*)((char*)B2s + seg * 1024),
                    16, 0, 0);
            }
            float b1v[4], csv[4];
            #pragma unroll
            for (int ct = 0; ct < 4; ++ct) {
                int col = c * 64 + ct * 16 + lr;
                b1v[ct] = (col < T_WIN) ? b1[col] : 0.f;
                csv[ct] = (col < T_WIN) ? cs[col] : 0.f;
            }
            __syncthreads();   // staging visible (vmcnt drained)

            f32x4 acc1[2][4];
            #pragma unroll
            for (int mt = 0; mt < 2; ++mt)
                #pragma unroll
                for (int ct = 0; ct < 4; ++ct) acc1[mt][ct] = zero4;

            #pragma unroll
            for (int kt = 0; kt < 11; ++kt) {
                #pragma unroll
                for (int ct = 0; ct < 4; ++ct) {
                    short8 bf = *(const short8*)&B1s[((kt * 4 + ct) * 64 + lane) * 8];
                    acc1[0][ct] = __builtin_amdgcn_mfma_f32_16x16x32_bf16(af[kt][0], bf, acc1[0][ct], 0, 0, 0);
                    acc1[1][ct] = __builtin_amdgcn_mfma_f32_16x16x32_bf16(af[kt][1], bf, acc1[1][ct], 0, 0, 0);
                }
            }

            // epilogue -> hs (wave-local rows; no extra barrier)
            #pragma unroll
            for (int mt = 0; mt < 2; ++mt)
                #pragma unroll
                for (int ct = 0; ct < 4; ++ct)
                    #pragma unroll
                    for (int r = 0; r < 4; ++r) {
                        int row = rw + mt * 16 + lq * 4 + r;
                        float pre = acc1[mt][ct][r] + b1v[ct] - llv[row] * csv[ct];
                        float e = __expf(2.f * pre);
                        float h = 1.f - 2.f * __builtin_amdgcn_rcpf(e + 1.f);
                        hs[row * 72 + ct * 16 + lr] = f2bf(h);
                    }

            #pragma unroll
            for (int kt2 = 0; kt2 < 2; ++kt2) {
                short8 a2[2];
                #pragma unroll
                for (int mt = 0; mt < 2; ++mt)
                    a2[mt] = *(const short8*)&hs[(rw + mt * 16 + lr) * 72 + kt2 * 32 + lq * 8];
                #pragma unroll
                for (int ct2 = 0; ct2 < 3; ++ct2) {
                    short8 bf2 = *(const short8*)&B2s[((kt2 * 3 + ct2) * 64 + lane) * 8];
                    acc2[0][ct2] = __builtin_amdgcn_mfma_f32_16x16x32_bf16(a2[0], bf2, acc2[0][ct2], 0, 0, 0);
                    acc2[1][ct2] = __builtin_amdgcn_mfma_f32_16x16x32_bf16(a2[1], bf2, acc2[1][ct2], 0, 0, 0);
                }
            }
        }

        float b2v[3];
        #pragma unroll
        for (int ct2 = 0; ct2 < 3; ++ct2) b2v[ct2] = b2[ct2 * 16 + lr];
        #pragma unroll
        for (int mt = 0; mt < 2; ++mt)
            #pragma unroll
            for (int ct2 = 0; ct2 < 3; ++ct2)
                #pragma unroll
                for (int r = 0; r < 4; ++r) {
                    int row = n0 + rw + mt * 16 + lq * 4 + r;
                    if (row < N)
                        outp[(size_t)row * T_OUT + ct2 * 16 + lr] = acc2[mt][ct2][r] + b2v[ct2];
                }
    }
}

__global__ __launch_bounds__(128) void loss2_kernel(
    const float* __restrict__ part, const int* __restrict__ lvp,
    float* __restrict__ out_loss, int T)
{
    __shared__ float red[128];
    red[threadIdx.x] = part[threadIdx.x];
    __syncthreads();
    for (int w = 64; w > 0; w >>= 1) {
        if (threadIdx.x < (unsigned)w) red[threadIdx.x] += red[threadIdx.x + w];
        __syncthreads();
    }
    if (threadIdx.x == 0) out_loss[0] = red[0] * (float)lvp[0] / (float)(T - 2);
}

extern "C" void kernel_launch(void* const* d_in, const int* in_sizes, int n_in,
                              void* d_out, int out_size, void* d_ws, size_t ws_size,
                              hipStream_t stream) {
    const float* x    = (const float*)d_in[0];
    const float* lvlc = (const float*)d_in[1];
    const float* seac = (const float*)d_in[2];
    const float* sp   = (const float*)d_in[3];
    const float* W1   = (const float*)d_in[4];
    const float* b1   = (const float*)d_in[5];
    const float* W2   = (const float*)d_in[6];
    const float* b2   = (const float*)d_in[7];
    const int*   lvp  = (const int*)d_in[10];

    int T = in_sizes[0];
    int N = T - T_WIN - T_OUT + 1;
    int NB = (N + BM - 1) / BM;

    short* W1F    = (short*)d_ws;                  // 264*512 shorts
    short* W2F    = W1F + 264 * 512;               // 36*512 shorts
    float* w_all  = (float*)(W2F + 36 * 512);      // T + 192
    float* levels = w_all + T + 192;               // T
    float* cs     = levels + T;                    // 352
    float* lpart  = cs + 352;                      // 128
    int*   flagsp = (int*)(lpart + 128);           // 4 flags on separate 128B lines

    float* outp  = (float*)d_out;
    float* lab   = outp + (size_t)N * T_OUT;
    float* lossp = lab + (size_t)N * T_OUT;

    init_flags<<<1, 64, 0, stream>>>(flagsp);
    fused_kernel<<<512, 256, 0, stream>>>(x, lvlc, seac, sp, W1, W2, b1, b2,
                                          W1F, W2F, w_all, levels, cs,
                                          outp, lab, lpart, flagsp, T, N, NB);
    loss2_kernel<<<1, 128, 0, stream>>>(lpart, lvp, lossp, T);
}

// Round 14
// 215.994 us; speedup vs baseline: 1.1152x; 1.0064x over previous
//
#include <hip/hip_runtime.h>
#include <hip/hip_bf16.h>

#define T_WIN 336
#define T_OUT 48
#define T_S   168
#define BM    128
#define CH    782

typedef __attribute__((ext_vector_type(8))) short short8;
typedef __attribute__((ext_vector_type(4))) float f32x4;

__device__ __forceinline__ short f2bf(float f) {
    union { float f; unsigned u; } v; v.f = f;
    unsigned r = v.u + 0x7FFFu + ((v.u >> 16) & 1u);
    return (short)(r >> 16);
}

template <int CTRL, int RMASK>
__device__ __forceinline__ float dppf(float v) {
    union { float f; int i; } in, out;
    in.f = v;
    out.i = __builtin_amdgcn_update_dpp(0, in.i, CTRL, RMASK, 0xf, true);
    return out.f;
}

// write-through relaxed agent store (prep outputs only; off critical path)
__device__ __forceinline__ void st_wt(float* p, float v) {
    __hip_atomic_store(p, v, __ATOMIC_RELAXED, __HIP_MEMORY_SCOPE_AGENT);
}
__device__ __forceinline__ void st_wt_u(unsigned* p, unsigned v) {
    __hip_atomic_store(p, v, __ATOMIC_RELAXED, __HIP_MEMORY_SCOPE_AGENT);
}

// XCD identity (XCC_ID, 4 bits). Wrong decode is SAFE: mismatch -> no park.
__device__ __forceinline__ int my_xcd_id() {
    unsigned xcc = __builtin_amdgcn_s_getreg((3 << 11) | (0 << 6) | 20);   // HW_REG_XCC_ID, 4b
    return (int)xcc + 1;                                                   // +1: 0 = "unset"
}

__global__ void init_flags(int* flags) {
    if (threadIdx.x < 4) flags[threadIdx.x * 32] = 0;
}

// ===================== fused persistent kernel =====================
// Round-22: XCD-park discriminator. r13 (depth-4 prefetch) was NEUTRAL vs
// depth-2 -> x-load starvation conclusively dead. Model rebuild: r0's
// standalone gemm was <88us (not in top-5) => per-tile latency ~40us, and
// production (7.6 tiles/us) < consumption capacity => wall ~= scan-under-load
// + 1 tile. Two fits: (i) scan stretched to ~135 by XCD-level L2 traffic
// (CU-park only fixed CU-level, +10us); (ii) scan ~105 + slow 40us tail.
// Single change vs r13: park ALL worker blocks sharing the scan's XCD
// (~64 of 510, 12.5%; capacity 446/40us = 11 tiles/us still > production)
// until the scan completes. (i) predicts fused ~110-125; (ii) predicts
// unchanged ~149 -> pivot to per-tile latency. Else byte-identical to r13.
__global__ __launch_bounds__(256, 2) void fused_kernel(
    const float* __restrict__ x, const float* __restrict__ lvl_coef,
    const float* __restrict__ seas_coef, const float* __restrict__ seas_params,
    const float* __restrict__ W1, const float* __restrict__ W2,
    const float* __restrict__ b1, const float* __restrict__ b2,
    short* __restrict__ W1F, short* __restrict__ W2F,
    float* __restrict__ w_all, float* __restrict__ levels,
    float* __restrict__ cs, float* __restrict__ outp,
    float* __restrict__ lab, float* __restrict__ lpart,
    int* flags, int T, int N, int NB)
{
    __shared__ float Lsf[512];
    __shared__ __align__(16) short Lbf0[512];
    __shared__ __align__(16) short Lbf1[512];
    __shared__ float llv[BM];
    __shared__ __align__(16) short hs[BM * 72];       // 18432 B (loss1 aliases this)
    __shared__ __align__(16) short B1s[11 * 4 * 512]; // 45056 B
    __shared__ __align__(16) short B2s[6 * 512];      // 6144 B
    __shared__ int sh_tk;

    int blk = blockIdx.x;
    int tid = threadIdx.x;
    int* progress  = flags;       // groups published; 1000 = all done
    int* prep_done = flags + 32;  // +128B: prep blocks finished (target 302)
    int* ticket    = flags + 64;  // +256B: dynamic tile dispenser
    int* scan_xcd  = flags + 96;  // +384B: scan block's XCD identity (+1)

    if (blk == 0) {
        // ---- serial ES scan (one wave, DPP affine scan, sync-free) ----
        if (tid >= 64) return;
        __builtin_amdgcn_s_setprio(3);
        int lane = tid;
        if (lane == 0)
            __hip_atomic_store(scan_xcd, my_xcd_id(), __ATOMIC_RELAXED, __HIP_MEMORY_SCOPE_AGENT);
        float a = 1.f / (1.f + __expf(-lvl_coef[0]));
        float g = 1.f / (1.f + __expf(-seas_coef[0]));
        float q = 1.f - a, gq = 1.f - g;

        for (int t = lane; t < T_S + 1; t += 64) w_all[t] = __expf(seas_params[t % T_S]);
        float lvl = x[0] / __expf(seas_params[0]);
        if (lane == 0) levels[0] = lvl;

        float wcur[3];
        #pragma unroll
        for (int i = 0; i < 3; ++i)
            wcur[i] = __expf(seas_params[(1 + 3 * lane + i) % T_S]);

        float f1 = q * q * q;
        float f2 = f1 * f1, f4 = f2 * f2, f8 = f4 * f4;
        float lnq = __logf(q);
        float P15 = __expf(3.f * (float)((lane & 15) + 1) * lnq);
        float P31 = __expf(3.f * (float)((lane & 31) + 1) * lnq);
        float pw3l = __expf(3.f * (float)lane * lnq);

        int j0 = 3 * lane;

        auto do_chunk = [&](float xv0, float xv1, float xv2, float* lev) {
            float rr[3];
            rr[0] = a * xv0 * __builtin_amdgcn_rcpf(wcur[0]);
            rr[1] = a * xv1 * __builtin_amdgcn_rcpf(wcur[1]);
            rr[2] = a * xv2 * __builtin_amdgcn_rcpf(wcur[2]);
            float S = fmaf(q, fmaf(q, rr[0], rr[1]), rr[2]);
            S = fmaf(f1, dppf<0x111, 0xf>(S), S);   // row_shr:1
            S = fmaf(f2, dppf<0x112, 0xf>(S), S);   // row_shr:2
            S = fmaf(f4, dppf<0x114, 0xf>(S), S);   // row_shr:4
            S = fmaf(f8, dppf<0x118, 0xf>(S), S);   // row_shr:8
            S = fmaf(P15, dppf<0x142, 0xa>(S), S);  // row_bcast:15 -> rows 1,3
            S = fmaf(P31, dppf<0x143, 0xc>(S), S);  // row_bcast:31 -> rows 2,3
            float E = dppf<0x138, 0xf>(S);          // wave_shr:1 (exclusive)
            float lv = fmaf(pw3l, lvl, E);
            #pragma unroll
            for (int i = 0; i < 3; ++i) { lv = fmaf(q, lv, rr[i]); lev[i] = lv; }
            { union { float f; int i; } uu; uu.i = __builtin_amdgcn_readlane(__builtin_bit_cast(int, lev[2]), 55); lvl = uu.f; }
            wcur[0] = fmaf(gq, wcur[0], g * xv0 * __builtin_amdgcn_rcpf(lev[0]));
            wcur[1] = fmaf(gq, wcur[1], g * xv1 * __builtin_amdgcn_rcpf(lev[1]));
            wcur[2] = fmaf(gq, wcur[2], g * xv2 * __builtin_amdgcn_rcpf(lev[2]));
        };

        // depth-4 static-slot prefetch pipeline (48 VGPR, <63 vmcnt cap, no shifts)
        float bufx[4][4][3];
        #pragma unroll
        for (int d = 0; d < 4; ++d)
            #pragma unroll
            for (int u = 0; u < 4; ++u)
                #pragma unroll
                for (int i = 0; i < 3; ++i)
                    bufx[d][u][i] = x[1 + T_S * (4 * d + u) + j0 + i];

        float* pl = levels + 1 + j0;
        float* pw = w_all + 1 + T_S + j0;

        for (int m = 0; m < 37; ++m) {
            #pragma unroll
            for (int s = 0; s < 4; ++s) {
                int grp = 4 * m + s;
                // publish every 8 groups (19 release drains total)
                if (grp && (grp & 7) == 0 && lane == 0)
                    __hip_atomic_store(progress, grp, __ATOMIC_RELEASE, __HIP_MEMORY_SCOPE_AGENT);

                // consume slot s into locals
                float xl[4][3];
                #pragma unroll
                for (int u = 0; u < 4; ++u)
                    #pragma unroll
                    for (int i = 0; i < 3; ++i)
                        xl[u][i] = bufx[s][u][i];

                // reissue prefetch for group grp+4 into slot s (static index)
                int gp = grp + 4;
                if (gp < 148) {
                    const float* pxg = x + 1 + (size_t)(4 * gp) * T_S + j0;
                    #pragma unroll
                    for (int u = 0; u < 4; ++u)
                        #pragma unroll
                        for (int i = 0; i < 3; ++i)
                            bufx[s][u][i] = pxg[u * T_S + i];
                } else {
                    #pragma unroll
                    for (int u = 0; u < 4; ++u)
                        #pragma unroll
                        for (int i = 0; i < 3; ++i) {
                            int t = 1 + T_S * (4 * gp + u) + j0 + i;
                            bufx[s][u][i] = x[min(t, T - 1)];
                        }
                }

                // serial chunk math + stores
                #pragma unroll
                for (int u = 0; u < 4; ++u) {
                    float lev[3];
                    do_chunk(xl[u][0], xl[u][1], xl[u][2], lev);
                    #pragma unroll
                    for (int i = 0; i < 3; ++i) {
                        pl[u * T_S + i] = lev[i];
                        pw[u * T_S + i] = wcur[i];
                    }
                }
                pl += 4 * T_S; pw += 4 * T_S;
            }
        }

        // tail: chunks 592..595 (bufx[0] holds group 148), guarded stores
        #pragma unroll
        for (int u = 0; u < 4; ++u) {
            int c = 592 + u;
            if (c * T_S >= T - 1) break;
            int len = (T - 1) - T_S * c; if (len > T_S) len = T_S;
            float lev[3];
            do_chunk(bufx[0][u][0], bufx[0][u][1], bufx[0][u][2], lev);
            #pragma unroll
            for (int i = 0; i < 3; ++i) {
                if (j0 + i < len) {
                    pl[u * T_S + i] = lev[i];
                    pw[u * T_S + i] = wcur[i];
                }
            }
        }
        if (lane == 0)
            __hip_atomic_store(progress, 1000, __ATOMIC_RELEASE, __HIP_MEMORY_SCOPE_AGENT);
        return;
    }

    if (blk <= 302) {
        if (blk >= 301) {              // ---- cs: colsum of W1 ----
            int k = (blk - 301) * 256 + tid;
            if (k < T_WIN) {
                float s = 0.f;
                for (int j = 0; j < T_WIN; ++j) s += W1[j * T_WIN + k];
                st_wt(&cs[k], s);
            }
        } else if (blk >= 265) {       // ---- W2F ----
            int d = (blk - 265) * 256 + tid;
            int j2 = d & 3, lane = (d >> 2) & 63, f = d >> 8;
            int ct2 = f % 3, rest = f / 3;
            int kt2 = rest & 1, c = rest >> 1;
            int k = c * 64 + kt2 * 32 + (lane >> 4) * 8 + 2 * j2;
            int o = ct2 * 16 + (lane & 15);
            unsigned short lo = 0, hi = 0;
            if (k     < T_WIN) lo = (unsigned short)f2bf(W2[k * T_OUT + o]);
            if (k + 1 < T_WIN) hi = (unsigned short)f2bf(W2[(k + 1) * T_OUT + o]);
            st_wt_u(&((unsigned*)W2F)[d], ((unsigned)hi << 16) | (unsigned)lo);
        } else {                       // ---- W1F ----
            int d = (blk - 1) * 256 + tid;
            int j2 = d & 3, lane = (d >> 2) & 63, f = d >> 8;
            int ct = f & 3, rest = f >> 2;
            int kt = rest % 11, c = rest / 11;
            int k = kt * 32 + (lane >> 4) * 8 + 2 * j2;
            int col = c * 64 + ct * 16 + (lane & 15);
            unsigned short lo = 0, hi = 0;
            if (col < T_WIN) {
                if (k     < T_WIN) lo = (unsigned short)f2bf(W1[k * T_WIN + col]);
                if (k + 1 < T_WIN) hi = (unsigned short)f2bf(W1[(k + 1) * T_WIN + col]);
            }
            st_wt_u(&((unsigned*)W1F)[d], ((unsigned)hi << 16) | (unsigned)lo);
        }
        __syncthreads();   // per-wave vmcnt drained before s_barrier
        if (tid == 0)
            __hip_atomic_fetch_add(prep_done, 1, __ATOMIC_RELAXED, __HIP_MEMORY_SCOPE_AGENT);
        // fall through to worker loop
    }

    // ================= worker loop (blocks 1..511) =================
    if (tid < 64) {
        while (__hip_atomic_load(prep_done, __ATOMIC_RELAXED, __HIP_MEMORY_SCOPE_AGENT) < 302)
            __builtin_amdgcn_s_sleep(16);
    }
    __syncthreads();   // W1F/W2F/cs at MALL; never stale-cached here

    int lane = tid & 63, wv = tid >> 6;
    int lr = lane & 15, lq = lane >> 4;
    int rw = wv * 32;
    int last_seen = 0;
    int NT = NB + 128;

    // ---- Round-22: park if this block shares the scan's XCD ----
    // Gives the scan a private XCD L2 (no staging reads / write-backs /
    // polling on it). ~64 blocks park; they rejoin for the tail drain.
    {
        int mine = my_xcd_id();
        if (__hip_atomic_load(scan_xcd, __ATOMIC_RELAXED, __HIP_MEMORY_SCOPE_AGENT) == mine) {
            while (__hip_atomic_load(progress, __ATOMIC_RELAXED, __HIP_MEMORY_SCOPE_AGENT) < 1000)
                __builtin_amdgcn_s_sleep(64);
            last_seen = 1000;
        }
    }

    for (;;) {
        __syncthreads();   // prior tile's LDS consumers done; sh_tk reusable
        if (tid == 0) sh_tk = atomicAdd(ticket, 1);
        __syncthreads();
        int tk = sh_tk;
        if (tk >= NT) return;

        // ---- ticket -> tile: interleave loss1 tiles 1-in-7 ----
        int sev = tk / 7;
        bool isl = (tk % 7 == 6) && (sev < 128);
        int tile = isl ? (NB + sev) : (tk - min(sev, 128));

        // ---- wait for scan frontier (+128-float pad for line tails) ----
        int need_t = (tile < NB) ? (tile * BM + 512 + 128)
                                 : ((tile - NB) * CH + CH + 2 + 128);
        if (need_t > T) need_t = T;
        int req = (need_t + 670) / 672;
        if (last_seen < req) {
            if (tid < 64) {
                while (__hip_atomic_load(progress, __ATOMIC_RELAXED, __HIP_MEMORY_SCOPE_AGENT) < req)
                    __builtin_amdgcn_s_sleep(32);
            }
            __syncthreads();
            last_seen = req;
        }

        if (tile >= NB) {
            // ---------------- loss1 tile ----------------
            float* ls  = (float*)hs;
            float* red = (float*)(hs + 4096);
            int lb = tile - NB;
            int lo = lb * CH;
            int n = T - lo; if (n > CH + 2) n = CH + 2;
            for (int i = tid; i < n; i += 256) ls[i] = __logf(levels[lo + i]);
            __syncthreads();
            float s = 0.f;
            int dmax = (T - 2) - lo; if (dmax > CH) dmax = CH;
            for (int i = tid; i < dmax; i += 256) {
                float d = ls[i + 2] - 2.f * ls[i + 1] + ls[i];
                s = fmaf(d, d, s);
            }
            red[tid] = s;
            __syncthreads();
            for (int w = 128; w > 0; w >>= 1) {
                if (tid < w) red[tid] += red[tid + w];
                __syncthreads();
            }
            if (tid == 0) lpart[lb] = red[0];
            continue;
        }

        // ---------------- gemm tile ----------------
        int n0 = tile * BM;
        float C = __logf(levels[min(n0 + T_WIN, T - 1)]);

        for (int i = tid; i < 512; i += 256) {
            int t = n0 + i;
            float v = (t < T) ? (__logf(x[t]) - __logf(w_all[t]) - C) : 0.f;
            Lsf[i] = v;
            Lbf0[i] = f2bf(v);
        }
        for (int i = tid; i < BM; i += 256) {
            int t = n0 + i + T_WIN;
            llv[i] = (t < T) ? (__logf(levels[t]) - C) : 0.f;
        }
        __syncthreads();
        for (int i = tid; i < 512; i += 256) Lbf1[i] = (i < 511) ? Lbf0[i + 1] : (short)0;
        __syncthreads();

        for (int u2 = tid; u2 < BM * T_OUT; u2 += 256) {
            int row = u2 / T_OUT, j = u2 - row * T_OUT;
            int nn = n0 + row;
            if (nn < N) lab[(size_t)nn * T_OUT + j] = Lsf[row + T_WIN + j] - llv[row];
        }

        // pack 22 A-fragments (parity arrays: 4B-aligned b32 reads)
        const short* abase = ((lr & 1) ? Lbf1 : Lbf0) + rw + (lr & ~1);
        short8 af[11][2];
        #pragma unroll
        for (int kt = 0; kt < 11; ++kt) {
            #pragma unroll
            for (int mt = 0; mt < 2; ++mt) {
                const int* ip = (const int*)(abase + mt * 16 + kt * 32 + lq * 8);
                union { short8 s; int i[4]; } u;
                u.i[0] = ip[0]; u.i[1] = ip[1]; u.i[2] = ip[2]; u.i[3] = ip[3];
                af[kt][mt] = u.s;
            }
        }

        f32x4 zero4 = {0.f, 0.f, 0.f, 0.f};
        f32x4 acc2[2][3];
        #pragma unroll
        for (int mt = 0; mt < 2; ++mt)
            #pragma unroll
            for (int ct = 0; ct < 3; ++ct) acc2[mt][ct] = zero4;

        #pragma unroll 1
        for (int c = 0; c < 6; ++c) {
            __syncthreads();   // previous chunk's B1s/B2s/hs consumers done

            const char* g1 = (const char*)(W1F + (size_t)c * 11 * 4 * 512);
            for (int seg = wv; seg < 44; seg += 4) {
                __builtin_amdgcn_global_load_lds(
                    (const __attribute__((address_space(1))) unsigned int*)(g1 + seg * 1024 + lane * 16),
                    (__attribute__((address_space(3))) unsigned int*)((char*)B1s + seg * 1024),
                    16, 0, 0);
            }
            const char* g2 = (const char*)(W2F + (size_t)c * 6 * 512);
            for (int seg = wv; seg < 6; seg += 4) {
                __builtin_amdgcn_global_load_lds(
                    (const __attribute__((address_space(1))) unsigned int*)(g2 + seg * 1024 + lane * 16),
                    (__attribute__((address_space(3))) unsigned int*)((char*)B2s + seg * 1024),
                    16, 0, 0);
            }
            float b1v[4], csv[4];
            #pragma unroll
            for (int ct = 0; ct < 4; ++ct) {
                int col = c * 64 + ct * 16 + lr;
                b1v[ct] = (col < T_WIN) ? b1[col] : 0.f;
                csv[ct] = (col < T_WIN) ? cs[col] : 0.f;
            }
            __syncthreads();   // staging visible (vmcnt drained)

            f32x4 acc1[2][4];
            #pragma unroll
            for (int mt = 0; mt < 2; ++mt)
                #pragma unroll
                for (int ct = 0; ct < 4; ++ct) acc1[mt][ct] = zero4;

            #pragma unroll
            for (int kt = 0; kt < 11; ++kt) {
                #pragma unroll
                for (int ct = 0; ct < 4; ++ct) {
                    short8 bf = *(const short8*)&B1s[((kt * 4 + ct) * 64 + lane) * 8];
                    acc1[0][ct] = __builtin_amdgcn_mfma_f32_16x16x32_bf16(af[kt][0], bf, acc1[0][ct], 0, 0, 0);
                    acc1[1][ct] = __builtin_amdgcn_mfma_f32_16x16x32_bf16(af[kt][1], bf, acc1[1][ct], 0, 0, 0);
                }
            }

            // epilogue -> hs (wave-local rows; no extra barrier)
            #pragma unroll
            for (int mt = 0; mt < 2; ++mt)
                #pragma unroll
                for (int ct = 0; ct < 4; ++ct)
                    #pragma unroll
                    for (int r = 0; r < 4; ++r) {
                        int row = rw + mt * 16 + lq * 4 + r;
                        float pre = acc1[mt][ct][r] + b1v[ct] - llv[row] * csv[ct];
                        float e = __expf(2.f * pre);
                        float h = 1.f - 2.f * __builtin_amdgcn_rcpf(e + 1.f);
                        hs[row * 72 + ct * 16 + lr] = f2bf(h);
                    }

            #pragma unroll
            for (int kt2 = 0; kt2 < 2; ++kt2) {
                short8 a2[2];
                #pragma unroll
                for (int mt = 0; mt < 2; ++mt)
                    a2[mt] = *(const short8*)&hs[(rw + mt * 16 + lr) * 72 + kt2 * 32 + lq * 8];
                #pragma unroll
                for (int ct2 = 0; ct2 < 3; ++ct2) {
                    short8 bf2 = *(const short8*)&B2s[((kt2 * 3 + ct2) * 64 + lane) * 8];
                    acc2[0][ct2] = __builtin_amdgcn_mfma_f32_16x16x32_bf16(a2[0], bf2, acc2[0][ct2], 0, 0, 0);
                    acc2[1][ct2] = __builtin_amdgcn_mfma_f32_16x16x32_bf16(a2[1], bf2, acc2[1][ct2], 0, 0, 0);
                }
            }
        }

        float b2v[3];
        #pragma unroll
        for (int ct2 = 0; ct2 < 3; ++ct2) b2v[ct2] = b2[ct2 * 16 + lr];
        #pragma unroll
        for (int mt = 0; mt < 2; ++mt)
            #pragma unroll
            for (int ct2 = 0; ct2 < 3; ++ct2)
                #pragma unroll
                for (int r = 0; r < 4; ++r) {
                    int row = n0 + rw + mt * 16 + lq * 4 + r;
                    if (row < N)
                        outp[(size_t)row * T_OUT + ct2 * 16 + lr] = acc2[mt][ct2][r] + b2v[ct2];
                }
    }
}

__global__ __launch_bounds__(128) void loss2_kernel(
    const float* __restrict__ part, const int* __restrict__ lvp,
    float* __restrict__ out_loss, int T)
{
    __shared__ float red[128];
    red[threadIdx.x] = part[threadIdx.x];
    __syncthreads();
    for (int w = 64; w > 0; w >>= 1) {
        if (threadIdx.x < (unsigned)w) red[threadIdx.x] += red[threadIdx.x + w];
        __syncthreads();
    }
    if (threadIdx.x == 0) out_loss[0] = red[0] * (float)lvp[0] / (float)(T - 2);
}

extern "C" void kernel_launch(void* const* d_in, const int* in_sizes, int n_in,
                              void* d_out, int out_size, void* d_ws, size_t ws_size,
                              hipStream_t stream) {
    const float* x    = (const float*)d_in[0];
    const float* lvlc = (const float*)d_in[1];
    const float* seac = (const float*)d_in[2];
    const float* sp   = (const float*)d_in[3];
    const float* W1   = (const float*)d_in[4];
    const float* b1   = (const float*)d_in[5];
    const float* W2   = (const float*)d_in[6];
    const float* b2   = (const float*)d_in[7];
    const int*   lvp  = (const int*)d_in[10];

    int T = in_sizes[0];
    int N = T - T_WIN - T_OUT + 1;
    int NB = (N + BM - 1) / BM;

    short* W1F    = (short*)d_ws;                  // 264*512 shorts
    short* W2F    = W1F + 264 * 512;               // 36*512 shorts
    float* w_all  = (float*)(W2F + 36 * 512);      // T + 192
    float* levels = w_all + T + 192;               // T
    float* cs     = levels + T;                    // 352
    float* lpart  = cs + 352;                      // 128
    int*   flagsp = (int*)(lpart + 128);           // 4 flags on separate 128B lines

    float* outp  = (float*)d_out;
    float* lab   = outp + (size_t)N * T_OUT;
    float* lossp = lab + (size_t)N * T_OUT;

    init_flags<<<1, 64, 0, stream>>>(flagsp);
    fused_kernel<<<512, 256, 0, stream>>>(x, lvlc, seac, sp, W1, W2, b1, b2,
                                          W1F, W2F, w_all, levels, cs,
                                          outp, lab, lpart, flagsp, T, N, NB);
    loss2_kernel<<<1, 128, 0, stream>>>(lpart, lvp, lossp, T);
}